// Round 3
// baseline (6245.658 us; speedup 1.0000x reference)
//
#include <hip/hip_runtime.h>

// SCRN: 2 layers of { xp = x@Wx^T+bx ; c_t = .05c+.95xp ; h_t = tanh(c@Uc^T + h@Vh^T) } + fc.
// EMA decay 0.05 -> 16-tap local filter (parallel). d = c@Uc^T parallel GEMM. Only
// h_t = tanh(d_t + h_{t-1}@Vh^T) is sequential: persistent 64-block kernel, Vh slice in LDS,
// h exchanged via LLC with agent-scope atomics + release/acquire fences + per-writer step flags.
// Input dtype (f32 vs bf16) detected AT RUNTIME by probing Wx0; all inputs converted to fp16
// workspace copies once; output written as bf16 or f32 per detected mode.

typedef _Float16 f16;
typedef _Float16 f16x8 __attribute__((ext_vector_type(8)));
typedef _Float16 f16x2 __attribute__((ext_vector_type(2)));
typedef float f32x4 __attribute__((ext_vector_type(4)));
typedef unsigned short u16;
typedef unsigned short u16x8 __attribute__((ext_vector_type(8)));
typedef unsigned long long u64;

#define DEV __device__ __forceinline__

constexpr int Tt = 512, HIDq = 512;

DEV float bf2f(u16 u) { unsigned v = ((unsigned)u) << 16; float f; __builtin_memcpy(&f, &v, 4); return f; }
DEV u16 f2bf(float f) { unsigned u; __builtin_memcpy(&u, &f, 4); u = (u + 0x7fffu + ((u >> 16) & 1u)) >> 16; return (u16)u; }
DEV float fast_tanh(float x) {
  x = fminf(30.f, fmaxf(-30.f, x));
  float e = exp2f(x * 2.885390081777927f);   // e^(2x)
  return (e - 1.f) / (e + 1.f);
}

// ---- dtype probe: Wx0 entries bounded by 1/16. bf16 decode of f32 mantissa halves -> huge. ----
__global__ void k_probe(const u16* __restrict__ w, int* __restrict__ dmode) {
  __shared__ int s;
  if (threadIdx.x == 0) s = 0;
  __syncthreads();
  int found = 0;
  for (int i = threadIdx.x; i < 8192; i += 256) {
    float v = bf2f(w[i]);
    if (fabsf(v) > 0.5f) found = 1;   // NaN compares false; plenty of huge finites in f32 mode
  }
  if (found) atomicOr(&s, 1);
  __syncthreads();
  if (threadIdx.x == 0) *dmode = s;   // 0 = bf16 buffers, 1 = f32 buffers
}

// ---- convert n8*8 elements (bf16 or f32 per mode) -> fp16 ----
__global__ void k_cvt(const void* __restrict__ src, f16* __restrict__ dst, int n8,
                      const int* __restrict__ dmode) {
  int i = blockIdx.x * 256 + threadIdx.x;
  if (i >= n8) return;
  f16x8 o;
  if (*dmode) {
    const float4* s = (const float4*)src;
    float4 a = s[2*i], b = s[2*i+1];
    o[0]=(f16)a.x; o[1]=(f16)a.y; o[2]=(f16)a.z; o[3]=(f16)a.w;
    o[4]=(f16)b.x; o[5]=(f16)b.y; o[6]=(f16)b.z; o[7]=(f16)b.w;
  } else {
    u16x8 v = ((const u16x8*)src)[i];
#pragma unroll
    for (int j = 0; j < 8; ++j) o[j] = (f16)bf2f(v[j]);
  }
  ((f16x8*)dst)[i] = o;
}

__global__ void k_zero(u16* __restrict__ out) {  // diagnostic fallback (ws too small)
  out[blockIdx.x * 256 + threadIdx.x] = 0;
}

// ---- EMA c_t = 0.05 c_{t-1} + 0.95 xp_t ; decay^16 ~ 1.5e-21 -> 16-step warmup per 64-chunk ----
__global__ __launch_bounds__(128) void k_ema(const f16* __restrict__ xp, f16* __restrict__ c) {
  int b = blockIdx.x >> 3, chunk = blockIdx.x & 7;
  int t0 = chunk * 64;
  int ch = threadIdx.x;  // pair index 0..127 (256 channels)
  const f16x2* src = (const f16x2*)(xp + (size_t)b * Tt * 256) + ch;
  f16x2* dst = (f16x2*)(c + (size_t)b * Tt * 256) + ch;
  float c0 = 0.f, c1 = 0.f;
  int ts = (t0 >= 16) ? t0 - 16 : 0;
  for (int tt = ts; tt < t0 + 64; ++tt) {
    f16x2 v = src[(size_t)tt * 128];
    c0 = 0.05f * c0 + 0.95f * (float)v.x;
    c1 = 0.05f * c1 + 0.95f * (float)v.y;
    if (tt >= t0) { f16x2 o; o.x = (f16)c0; o.y = (f16)c1; dst[(size_t)tt * 128] = o; }
  }
}

// ---- GEMM: C[M,N] = A[M,K] @ B[N,K]^T (+bias), all fp16 in, fp16 out. 128x128x32 tiles ----
template<bool HAS_BIAS>
__global__ __launch_bounds__(256) void k_gemm(const f16* __restrict__ A, const f16* __restrict__ Bm,
                                              const f16* __restrict__ bias, f16* __restrict__ C,
                                              int M, int N, int K) {
  __shared__ f16 As[128][40];
  __shared__ f16 Bs[128][40];
  const int tid = threadIdx.x, lane = tid & 63, wv = tid >> 6;
  const int l15 = lane & 15, q = lane >> 4;
  const int wm = wv >> 1, wn = wv & 1;
  const int m0 = blockIdx.y * 128, n0 = blockIdx.x * 128;
  const int srow = tid >> 1, sseg = tid & 1;
  f32x4 acc[4][4] = {};
  const f16* ga = A  + (size_t)(m0 + srow) * K + sseg * 16;
  const f16* gb = Bm + (size_t)(n0 + srow) * K + sseg * 16;
  for (int k0 = 0; k0 < K; k0 += 32) {
    f16x8 a0 = *(const f16x8*)(ga + k0);
    f16x8 a1 = *(const f16x8*)(ga + k0 + 8);
    f16x8 b0 = *(const f16x8*)(gb + k0);
    f16x8 b1 = *(const f16x8*)(gb + k0 + 8);
    __syncthreads();
    *(f16x8*)&As[srow][sseg*16]     = a0;
    *(f16x8*)&As[srow][sseg*16 + 8] = a1;
    *(f16x8*)&Bs[srow][sseg*16]     = b0;
    *(f16x8*)&Bs[srow][sseg*16 + 8] = b1;
    __syncthreads();
    f16x8 af[4], bf[4];
#pragma unroll
    for (int i = 0; i < 4; ++i) af[i] = *(const f16x8*)&As[wm*64 + i*16 + l15][q*8];
#pragma unroll
    for (int i = 0; i < 4; ++i) bf[i] = *(const f16x8*)&Bs[wn*64 + i*16 + l15][q*8];
#pragma unroll
    for (int i = 0; i < 4; ++i)
#pragma unroll
      for (int j = 0; j < 4; ++j)
        acc[i][j] = __builtin_amdgcn_mfma_f32_16x16x32_f16(af[i], bf[j], acc[i][j], 0, 0, 0);
  }
#pragma unroll
  for (int j = 0; j < 4; ++j) {
    int col = n0 + wn*64 + j*16 + l15;
    float bv = HAS_BIAS ? (float)bias[col] : 0.f;
#pragma unroll
    for (int i = 0; i < 4; ++i)
#pragma unroll
      for (int r = 0; r < 4; ++r) {
        int row = m0 + wm*64 + i*16 + q*4 + r;
        C[(size_t)row * N + col] = (f16)(acc[i][j][r] + bv);
      }
  }
}

// ---- sequential recurrence: h_t = tanh(d_t + h_{t-1} @ Vh^T) ----
// 64 blocks = 16 hid-slices(32 cols) x 4 batch-groups(16 rows); 128 thr = 2 waves.
__global__ __launch_bounds__(128) void k_scan(const f16* __restrict__ Vh, const f16* __restrict__ d16,
                                              f16* __restrict__ hbuf, int* __restrict__ flags,
                                              f16* __restrict__ hs_out) {
  __shared__ f16 VhS[32][520];
  __shared__ f16 tr[2][16][20];
  const int bid = blockIdx.x, m = bid & 15, g = bid >> 4;
  const int tid = threadIdx.x, wv = tid >> 6, lane = tid & 63;
  const int l15 = lane & 15, q = lane >> 4;

  for (int i = tid; i < 32 * 64; i += 128) {
    int r = i >> 6, c = (i & 63) * 8;
    *(f16x8*)&VhS[r][c] = *(const f16x8*)&Vh[(size_t)(32*m + r) * HIDq + c];
  }
  {
    int r = tid >> 3, c4 = (tid & 7) * 4;
    __hip_atomic_store((u64*)&hbuf[(size_t)(64 + 16*g + r) * HIDq + 32*m + c4], 0ULL,
                       __ATOMIC_RELAXED, __HIP_MEMORY_SCOPE_AGENT);
  }
  __builtin_amdgcn_fence(__ATOMIC_RELEASE, "agent");
  __syncthreads();
  if (tid == 0)
    __hip_atomic_store(&flags[(g*16 + m) * 32], 0, __ATOMIC_RELAXED, __HIP_MEMORY_SCOPE_AGENT);

  const int myrow_t = 16*g + (lane >> 2);
  const int mycol_t = 32*m + 16*wv + (lane & 3) * 4;

  for (int t = 0; t < Tt; ++t) {
    const int p = t & 1, pm1 = p ^ 1;
    float dv[4];
    {
      const f16* dbase = d16 + ((size_t)(16*g + q*4) * Tt + t) * HIDq + 32*m + 16*wv + l15;
#pragma unroll
      for (int r = 0; r < 4; ++r) dv[r] = (float)dbase[(size_t)r * Tt * HIDq];
    }
    if (lane < 16) {
      const int* fp = &flags[(g*16 + lane) * 32];
      while (__hip_atomic_load(fp, __ATOMIC_RELAXED, __HIP_MEMORY_SCOPE_AGENT) < t) {}
    }
    __builtin_amdgcn_fence(__ATOMIC_ACQUIRE, "agent");
    f32x4 acc0 = {}, acc1 = {};
    const u64* hrow = (const u64*)(hbuf + (size_t)(pm1*64 + 16*g + l15) * HIDq);
#pragma unroll
    for (int kk = 0; kk < 16; ++kk) {
      union { u64 u[2]; f16x8 v; } ua;
      ua.u[0] = __hip_atomic_load(hrow + kk*8 + q*2,     __ATOMIC_RELAXED, __HIP_MEMORY_SCOPE_AGENT);
      ua.u[1] = __hip_atomic_load(hrow + kk*8 + q*2 + 1, __ATOMIC_RELAXED, __HIP_MEMORY_SCOPE_AGENT);
      f16x8 bfr = *(const f16x8*)&VhS[16*wv + l15][kk*32 + q*8];
      if (kk & 1) acc1 = __builtin_amdgcn_mfma_f32_16x16x32_f16(ua.v, bfr, acc1, 0, 0, 0);
      else        acc0 = __builtin_amdgcn_mfma_f32_16x16x32_f16(ua.v, bfr, acc0, 0, 0, 0);
    }
#pragma unroll
    for (int r = 0; r < 4; ++r) {
      float z = acc0[r] + acc1[r] + dv[r];
      tr[wv][q*4 + r][l15] = (f16)fast_tanh(z);
    }
    asm volatile("s_waitcnt lgkmcnt(0)" ::: "memory");
    u64 pkt = *(const u64*)&tr[wv][lane >> 2][(lane & 3) * 4];
    __hip_atomic_store((u64*)&hbuf[(size_t)(p*64 + myrow_t) * HIDq + mycol_t], pkt,
                       __ATOMIC_RELAXED, __HIP_MEMORY_SCOPE_AGENT);
    if (hs_out)
      __builtin_nontemporal_store(pkt, (u64*)&hs_out[((size_t)myrow_t * Tt + t) * HIDq + mycol_t]);
    __builtin_amdgcn_fence(__ATOMIC_RELEASE, "agent");
    __syncthreads();
    if (tid == 0)
      __hip_atomic_store(&flags[(g*16 + m) * 32], t + 1, __ATOMIC_RELAXED, __HIP_MEMORY_SCOPE_AGENT);
  }
}

// ---- final: out[64,128] = h_last[64,512] @ fc_w[128,512]^T + fc_b; out dtype per mode ----
__global__ __launch_bounds__(64) void k_final(const f16* __restrict__ h, const f16* __restrict__ fw,
                                              const f16* __restrict__ fb, void* __restrict__ outv,
                                              const int* __restrict__ dmode) {
  __shared__ f16 hA[16][520];
  __shared__ f16 Bw[16][520];
  const int mb = blockIdx.x & 3, nb = blockIdx.x >> 2;
  const int lane = threadIdx.x, l15 = lane & 15, q = lane >> 4;
  for (int i = lane; i < 16 * 64; i += 64) {
    int r = i >> 6, c = (i & 63) * 8;
    *(f16x8*)&hA[r][c] = *(const f16x8*)&h[(size_t)(mb*16 + r) * 512 + c];
    *(f16x8*)&Bw[r][c] = *(const f16x8*)&fw[(size_t)(nb*16 + r) * 512 + c];
  }
  __syncthreads();
  f32x4 acc = {};
#pragma unroll
  for (int kk = 0; kk < 16; ++kk) {
    f16x8 a = *(const f16x8*)&hA[l15][kk*32 + q*8];
    f16x8 b = *(const f16x8*)&Bw[l15][kk*32 + q*8];
    acc = __builtin_amdgcn_mfma_f32_16x16x32_f16(a, b, acc, 0, 0, 0);
  }
  float bv = (float)fb[nb*16 + l15];
  int md = *dmode;
#pragma unroll
  for (int r = 0; r < 4; ++r) {
    int idx = (mb*16 + q*4 + r) * 128 + nb*16 + l15;
    float val = acc[r] + bv;
    if (md) ((float*)outv)[idx] = val;
    else    ((u16*)outv)[idx]   = f2bf(val);
  }
}

extern "C" void kernel_launch(void* const* d_in, const int* in_sizes, int n_in,
                              void* d_out, int out_size, void* d_ws, size_t ws_size,
                              hipStream_t stream) {
  if (ws_size < 88080384ull) {  // need 84 MB; distinctive zero output if not
    k_zero<<<32, 256, 0, stream>>>((u16*)d_out);
    return;
  }
  char* ws = (char*)d_ws;
  f16* hb1   = (f16*)(ws + 0);
  f16* hb2   = (f16*)(ws + 131072);
  int* fl1   = (int*)(ws + 262144);
  int* fl2   = (int*)(ws + 270336);
  int* dmode = (int*)(ws + 278528);
  f16* Wx0f = (f16*)(ws + 1048576);
  f16* Uc0f = (f16*)(ws + 1179648);
  f16* Vh0f = (f16*)(ws + 1441792);
  f16* Wx1f = (f16*)(ws + 1966080);
  f16* Uc1f = (f16*)(ws + 2228224);
  f16* Vh1f = (f16*)(ws + 2490368);
  f16* fcwf = (f16*)(ws + 3014656);
  f16* bx0f = (f16*)(ws + 3145728);
  f16* bx1f = (f16*)(ws + 3146240);
  f16* fcbf = (f16*)(ws + 3146752);
  f16* x16  = (f16*)(ws + 4194304);    // 16 MB
  f16* A    = (f16*)(ws + 20971520);   // 32 MB: db1 | xp2+cb2
  f16* Xb   = (f16*)(ws + 54525952);   // 32 MB: xp1+cb1 | hs1 | db2
  f16* xp1 = Xb;
  f16* cb1 = Xb + 8388608;
  f16* db1 = A;
  f16* hs1 = Xb;
  f16* xp2 = A;
  f16* cb2 = A + 8388608;
  f16* db2 = Xb;

  hipMemsetAsync(fl1, 0xFF, 8192, stream);
  hipMemsetAsync(fl2, 0xFF, 8192, stream);

  k_probe<<<1, 256, 0, stream>>>((const u16*)d_in[1], dmode);
  auto cvt = [&](const void* s, f16* d, int n) {
    int n8 = n / 8;
    k_cvt<<<dim3((n8 + 255) / 256), dim3(256), 0, stream>>>(s, d, n8, dmode);
  };
  cvt(d_in[0],  x16,  8388608);
  cvt(d_in[1],  Wx0f, 65536);
  cvt(d_in[2],  bx0f, 256);
  cvt(d_in[3],  Uc0f, 131072);
  cvt(d_in[4],  Vh0f, 262144);
  cvt(d_in[5],  Wx1f, 131072);
  cvt(d_in[6],  bx1f, 256);
  cvt(d_in[7],  Uc1f, 131072);
  cvt(d_in[8],  Vh1f, 262144);
  cvt(d_in[9],  fcwf, 65536);
  cvt(d_in[10], fcbf, 128);

  // layer 1
  k_gemm<true ><<<dim3(2, 256), 256, 0, stream>>>(x16, Wx0f, bx0f, xp1, 32768, 256, 256);
  k_ema<<<512, 128, 0, stream>>>(xp1, cb1);
  k_gemm<false><<<dim3(4, 256), 256, 0, stream>>>(cb1, Uc0f, nullptr, db1, 32768, 512, 256);
  k_scan<<<64, 128, 0, stream>>>(Vh0f, db1, hb1, fl1, hs1);
  // layer 2
  k_gemm<true ><<<dim3(2, 256), 256, 0, stream>>>(hs1, Wx1f, bx1f, xp2, 32768, 256, 512);
  k_ema<<<512, 128, 0, stream>>>(xp2, cb2);
  k_gemm<false><<<dim3(4, 256), 256, 0, stream>>>(cb2, Uc1f, nullptr, db2, 32768, 512, 256);
  k_scan<<<64, 128, 0, stream>>>(Vh1f, db2, hb2, fl2, nullptr);
  // head: h_511 (t=511 -> parity 1) is in the parity-1 half of hb2
  k_final<<<32, 64, 0, stream>>>(hb2 + 64 * 512, fcwf, fcbf, d_out, dmode);
}

// Round 4
// 3861.909 us; speedup vs baseline: 1.6172x; 1.6172x over previous
//
#include <hip/hip_runtime.h>

// SCRN: 2 layers of { xp = x@Wx^T+bx ; c_t = .05c+.95xp ; h_t = tanh(c@Uc^T + h@Vh^T) } + fc.
// EMA decay 0.05 -> 16-tap local filter (parallel). d = c@Uc^T parallel GEMM. Only
// h_t = tanh(d_t + h_{t-1}@Vh^T) is sequential: persistent 64-block kernel, Vh slice in LDS.
// h exchange: sc1 agent-scope relaxed atomics (bypass L1/L2, complete at LLC) + per-writer step
// flags. Producer order: data stores -> s_waitcnt vmcnt(0) -> flag store. NO cache-maintenance
// fences (round-3 lesson: agent fences lower to buffer_wbl2/inv = ~6.9us/step, 0.2% MfmaUtil).
// Input dtype (f32 vs bf16) runtime-probed; all inputs converted once to fp16; fp32 accum.

typedef _Float16 f16;
typedef _Float16 f16x8 __attribute__((ext_vector_type(8)));
typedef _Float16 f16x2 __attribute__((ext_vector_type(2)));
typedef float f32x4 __attribute__((ext_vector_type(4)));
typedef unsigned short u16;
typedef unsigned short u16x8 __attribute__((ext_vector_type(8)));
typedef unsigned long long u64;

#define DEV __device__ __forceinline__

constexpr int Tt = 512, HIDq = 512;

DEV float bf2f(u16 u) { unsigned v = ((unsigned)u) << 16; float f; __builtin_memcpy(&f, &v, 4); return f; }
DEV u16 f2bf(float f) { unsigned u; __builtin_memcpy(&u, &f, 4); u = (u + 0x7fffu + ((u >> 16) & 1u)) >> 16; return (u16)u; }
DEV float fast_tanh(float x) {
  x = fminf(30.f, fmaxf(-30.f, x));
  float e = exp2f(x * 2.885390081777927f);   // e^(2x)
  return (e - 1.f) / (e + 1.f);
}

// ---- dtype probe: Wx0 entries bounded by 1/16. bf16 decode of f32 mantissa halves -> huge. ----
__global__ void k_probe(const u16* __restrict__ w, int* __restrict__ dmode) {
  __shared__ int s;
  if (threadIdx.x == 0) s = 0;
  __syncthreads();
  int found = 0;
  for (int i = threadIdx.x; i < 8192; i += 256) {
    float v = bf2f(w[i]);
    if (fabsf(v) > 0.5f) found = 1;
  }
  if (found) atomicOr(&s, 1);
  __syncthreads();
  if (threadIdx.x == 0) *dmode = s;   // 0 = bf16 buffers, 1 = f32 buffers
}

// ---- convert n8*8 elements (bf16 or f32 per mode) -> fp16 ----
__global__ void k_cvt(const void* __restrict__ src, f16* __restrict__ dst, int n8,
                      const int* __restrict__ dmode) {
  int i = blockIdx.x * 256 + threadIdx.x;
  if (i >= n8) return;
  f16x8 o;
  if (*dmode) {
    const float4* s = (const float4*)src;
    float4 a = s[2*i], b = s[2*i+1];
    o[0]=(f16)a.x; o[1]=(f16)a.y; o[2]=(f16)a.z; o[3]=(f16)a.w;
    o[4]=(f16)b.x; o[5]=(f16)b.y; o[6]=(f16)b.z; o[7]=(f16)b.w;
  } else {
    u16x8 v = ((const u16x8*)src)[i];
#pragma unroll
    for (int j = 0; j < 8; ++j) o[j] = (f16)bf2f(v[j]);
  }
  ((f16x8*)dst)[i] = o;
}

__global__ void k_zero(u16* __restrict__ out) {  // diagnostic fallback (ws too small)
  out[blockIdx.x * 256 + threadIdx.x] = 0;
}

// ---- EMA c_t = 0.05 c_{t-1} + 0.95 xp_t ; decay^16 ~ 1.5e-21 -> 16-step warmup per 64-chunk ----
__global__ __launch_bounds__(128) void k_ema(const f16* __restrict__ xp, f16* __restrict__ c) {
  int b = blockIdx.x >> 3, chunk = blockIdx.x & 7;
  int t0 = chunk * 64;
  int ch = threadIdx.x;  // pair index 0..127 (256 channels)
  const f16x2* src = (const f16x2*)(xp + (size_t)b * Tt * 256) + ch;
  f16x2* dst = (f16x2*)(c + (size_t)b * Tt * 256) + ch;
  float c0 = 0.f, c1 = 0.f;
  int ts = (t0 >= 16) ? t0 - 16 : 0;
  for (int tt = ts; tt < t0 + 64; ++tt) {
    f16x2 v = src[(size_t)tt * 128];
    c0 = 0.05f * c0 + 0.95f * (float)v.x;
    c1 = 0.05f * c1 + 0.95f * (float)v.y;
    if (tt >= t0) { f16x2 o; o.x = (f16)c0; o.y = (f16)c1; dst[(size_t)tt * 128] = o; }
  }
}

// ---- GEMM: C[M,N] = A[M,K] @ B[N,K]^T (+bias), all fp16 in, fp16 out. 128x128x32 tiles ----
template<bool HAS_BIAS>
__global__ __launch_bounds__(256) void k_gemm(const f16* __restrict__ A, const f16* __restrict__ Bm,
                                              const f16* __restrict__ bias, f16* __restrict__ C,
                                              int M, int N, int K) {
  __shared__ f16 As[128][40];
  __shared__ f16 Bs[128][40];
  const int tid = threadIdx.x, lane = tid & 63, wv = tid >> 6;
  const int l15 = lane & 15, q = lane >> 4;
  const int wm = wv >> 1, wn = wv & 1;
  const int m0 = blockIdx.y * 128, n0 = blockIdx.x * 128;
  const int srow = tid >> 1, sseg = tid & 1;
  f32x4 acc[4][4] = {};
  const f16* ga = A  + (size_t)(m0 + srow) * K + sseg * 16;
  const f16* gb = Bm + (size_t)(n0 + srow) * K + sseg * 16;
  for (int k0 = 0; k0 < K; k0 += 32) {
    f16x8 a0 = *(const f16x8*)(ga + k0);
    f16x8 a1 = *(const f16x8*)(ga + k0 + 8);
    f16x8 b0 = *(const f16x8*)(gb + k0);
    f16x8 b1 = *(const f16x8*)(gb + k0 + 8);
    __syncthreads();
    *(f16x8*)&As[srow][sseg*16]     = a0;
    *(f16x8*)&As[srow][sseg*16 + 8] = a1;
    *(f16x8*)&Bs[srow][sseg*16]     = b0;
    *(f16x8*)&Bs[srow][sseg*16 + 8] = b1;
    __syncthreads();
    f16x8 af[4], bf[4];
#pragma unroll
    for (int i = 0; i < 4; ++i) af[i] = *(const f16x8*)&As[wm*64 + i*16 + l15][q*8];
#pragma unroll
    for (int i = 0; i < 4; ++i) bf[i] = *(const f16x8*)&Bs[wn*64 + i*16 + l15][q*8];
#pragma unroll
    for (int i = 0; i < 4; ++i)
#pragma unroll
      for (int j = 0; j < 4; ++j)
        acc[i][j] = __builtin_amdgcn_mfma_f32_16x16x32_f16(af[i], bf[j], acc[i][j], 0, 0, 0);
  }
#pragma unroll
  for (int j = 0; j < 4; ++j) {
    int col = n0 + wn*64 + j*16 + l15;
    float bv = HAS_BIAS ? (float)bias[col] : 0.f;
#pragma unroll
    for (int i = 0; i < 4; ++i)
#pragma unroll
      for (int r = 0; r < 4; ++r) {
        int row = m0 + wm*64 + i*16 + q*4 + r;
        C[(size_t)row * N + col] = (f16)(acc[i][j][r] + bv);
      }
  }
}

// ---- sequential recurrence: h_t = tanh(d_t + h_{t-1} @ Vh^T) ----
// 64 blocks = 16 hid-slices(32 cols) x 4 batch-groups(16 rows); 128 thr = 2 waves.
__global__ __launch_bounds__(128) void k_scan(const f16* __restrict__ Vh, const f16* __restrict__ d16,
                                              f16* __restrict__ hbuf, int* __restrict__ flags,
                                              f16* __restrict__ hs_out) {
  __shared__ f16 VhS[32][520];
  __shared__ f16 tr[2][16][20];
  const int bid = blockIdx.x, m = bid & 15, g = bid >> 4;
  const int tid = threadIdx.x, wv = tid >> 6, lane = tid & 63;
  const int l15 = lane & 15, q = lane >> 4;

  for (int i = tid; i < 32 * 64; i += 128) {
    int r = i >> 6, c = (i & 63) * 8;
    *(f16x8*)&VhS[r][c] = *(const f16x8*)&Vh[(size_t)(32*m + r) * HIDq + c];
  }
  {
    int r = tid >> 3, c4 = (tid & 7) * 4;
    __hip_atomic_store((u64*)&hbuf[(size_t)(64 + 16*g + r) * HIDq + 32*m + c4], 0ULL,
                       __ATOMIC_RELAXED, __HIP_MEMORY_SCOPE_AGENT);
  }
  asm volatile("s_waitcnt vmcnt(0)" ::: "memory");   // h-init at LLC before flag
  __syncthreads();
  if (tid == 0)
    __hip_atomic_store(&flags[(g*16 + m) * 32], 0, __ATOMIC_RELAXED, __HIP_MEMORY_SCOPE_AGENT);

  const int myrow_t = 16*g + (lane >> 2);
  const int mycol_t = 32*m + 16*wv + (lane & 3) * 4;

  for (int t = 0; t < Tt; ++t) {
    const int p = t & 1, pm1 = p ^ 1;
    // d_t prefetch: independent of h, stays in flight across the spin
    float dv[4];
    {
      const f16* dbase = d16 + ((size_t)(16*g + q*4) * Tt + t) * HIDq + 32*m + 16*wv + l15;
#pragma unroll
      for (int r = 0; r < 4; ++r) dv[r] = (float)dbase[(size_t)r * Tt * HIDq];
    }
    // wait for all 16 producers of my batch group (flag >= t)
    if (lane < 16) {
      const int* fp = &flags[(g*16 + lane) * 32];
      while (__hip_atomic_load(fp, __ATOMIC_RELAXED, __HIP_MEMORY_SCOPE_AGENT) < t) {}
    }
    asm volatile("" ::: "memory");   // compiler barrier only: no hoisting of h loads above spin
    // A-fragments straight from LLC (sc1 relaxed atomic u64 pairs), B from LDS; K=512
    f32x4 acc0 = {}, acc1 = {};
    const u64* hrow = (const u64*)(hbuf + (size_t)(pm1*64 + 16*g + l15) * HIDq);
#pragma unroll
    for (int kk = 0; kk < 16; ++kk) {
      union { u64 u[2]; f16x8 v; } ua;
      ua.u[0] = __hip_atomic_load(hrow + kk*8 + q*2,     __ATOMIC_RELAXED, __HIP_MEMORY_SCOPE_AGENT);
      ua.u[1] = __hip_atomic_load(hrow + kk*8 + q*2 + 1, __ATOMIC_RELAXED, __HIP_MEMORY_SCOPE_AGENT);
      f16x8 bfr = *(const f16x8*)&VhS[16*wv + l15][kk*32 + q*8];
      if (kk & 1) acc1 = __builtin_amdgcn_mfma_f32_16x16x32_f16(ua.v, bfr, acc1, 0, 0, 0);
      else        acc0 = __builtin_amdgcn_mfma_f32_16x16x32_f16(ua.v, bfr, acc0, 0, 0, 0);
    }
#pragma unroll
    for (int r = 0; r < 4; ++r) {
      float z = acc0[r] + acc1[r] + dv[r];
      tr[wv][q*4 + r][l15] = (f16)fast_tanh(z);
    }
    asm volatile("s_waitcnt lgkmcnt(0)" ::: "memory");
    u64 pkt = *(const u64*)&tr[wv][lane >> 2][(lane & 3) * 4];
    __hip_atomic_store((u64*)&hbuf[(size_t)(p*64 + myrow_t) * HIDq + mycol_t], pkt,
                       __ATOMIC_RELAXED, __HIP_MEMORY_SCOPE_AGENT);
    if (hs_out)   // plain store: retires at L2, kernel-boundary writeback publishes to next GEMM
      *(u64*)&hs_out[((size_t)myrow_t * Tt + t) * HIDq + mycol_t] = pkt;
    asm volatile("s_waitcnt vmcnt(0)" ::: "memory");   // h at LLC before flag publish
    __syncthreads();
    if (tid == 0)
      __hip_atomic_store(&flags[(g*16 + m) * 32], t + 1, __ATOMIC_RELAXED, __HIP_MEMORY_SCOPE_AGENT);
  }
}

// ---- final: out[64,128] = h_last[64,512] @ fc_w[128,512]^T + fc_b; out dtype per mode ----
__global__ __launch_bounds__(64) void k_final(const f16* __restrict__ h, const f16* __restrict__ fw,
                                              const f16* __restrict__ fb, void* __restrict__ outv,
                                              const int* __restrict__ dmode) {
  __shared__ f16 hA[16][520];
  __shared__ f16 Bw[16][520];
  const int mb = blockIdx.x & 3, nb = blockIdx.x >> 2;
  const int lane = threadIdx.x, l15 = lane & 15, q = lane >> 4;
  for (int i = lane; i < 16 * 64; i += 64) {
    int r = i >> 6, c = (i & 63) * 8;
    *(f16x8*)&hA[r][c] = *(const f16x8*)&h[(size_t)(mb*16 + r) * 512 + c];
    *(f16x8*)&Bw[r][c] = *(const f16x8*)&fw[(size_t)(nb*16 + r) * 512 + c];
  }
  __syncthreads();
  f32x4 acc = {};
#pragma unroll
  for (int kk = 0; kk < 16; ++kk) {
    f16x8 a = *(const f16x8*)&hA[l15][kk*32 + q*8];
    f16x8 b = *(const f16x8*)&Bw[l15][kk*32 + q*8];
    acc = __builtin_amdgcn_mfma_f32_16x16x32_f16(a, b, acc, 0, 0, 0);
  }
  float bv = (float)fb[nb*16 + l15];
  int md = *dmode;
#pragma unroll
  for (int r = 0; r < 4; ++r) {
    int idx = (mb*16 + q*4 + r) * 128 + nb*16 + l15;
    float val = acc[r] + bv;
    if (md) ((float*)outv)[idx] = val;
    else    ((u16*)outv)[idx]   = f2bf(val);
  }
}

extern "C" void kernel_launch(void* const* d_in, const int* in_sizes, int n_in,
                              void* d_out, int out_size, void* d_ws, size_t ws_size,
                              hipStream_t stream) {
  if (ws_size < 88080384ull) {
    k_zero<<<32, 256, 0, stream>>>((u16*)d_out);
    return;
  }
  char* ws = (char*)d_ws;
  f16* hb1   = (f16*)(ws + 0);
  f16* hb2   = (f16*)(ws + 131072);
  int* fl1   = (int*)(ws + 262144);
  int* fl2   = (int*)(ws + 270336);
  int* dmode = (int*)(ws + 278528);
  f16* Wx0f = (f16*)(ws + 1048576);
  f16* Uc0f = (f16*)(ws + 1179648);
  f16* Vh0f = (f16*)(ws + 1441792);
  f16* Wx1f = (f16*)(ws + 1966080);
  f16* Uc1f = (f16*)(ws + 2228224);
  f16* Vh1f = (f16*)(ws + 2490368);
  f16* fcwf = (f16*)(ws + 3014656);
  f16* bx0f = (f16*)(ws + 3145728);
  f16* bx1f = (f16*)(ws + 3146240);
  f16* fcbf = (f16*)(ws + 3146752);
  f16* x16  = (f16*)(ws + 4194304);    // 16 MB
  f16* A    = (f16*)(ws + 20971520);   // 32 MB: db1 | xp2+cb2
  f16* Xb   = (f16*)(ws + 54525952);   // 32 MB: xp1+cb1 | hs1 | db2
  f16* xp1 = Xb;
  f16* cb1 = Xb + 8388608;
  f16* db1 = A;
  f16* hs1 = Xb;
  f16* xp2 = A;
  f16* cb2 = A + 8388608;
  f16* db2 = Xb;

  hipMemsetAsync(fl1, 0xFF, 8192, stream);
  hipMemsetAsync(fl2, 0xFF, 8192, stream);

  k_probe<<<1, 256, 0, stream>>>((const u16*)d_in[1], dmode);
  auto cvt = [&](const void* s, f16* d, int n) {
    int n8 = n / 8;
    k_cvt<<<dim3((n8 + 255) / 256), dim3(256), 0, stream>>>(s, d, n8, dmode);
  };
  cvt(d_in[0],  x16,  8388608);
  cvt(d_in[1],  Wx0f, 65536);
  cvt(d_in[2],  bx0f, 256);
  cvt(d_in[3],  Uc0f, 131072);
  cvt(d_in[4],  Vh0f, 262144);
  cvt(d_in[5],  Wx1f, 131072);
  cvt(d_in[6],  bx1f, 256);
  cvt(d_in[7],  Uc1f, 131072);
  cvt(d_in[8],  Vh1f, 262144);
  cvt(d_in[9],  fcwf, 65536);
  cvt(d_in[10], fcbf, 128);

  // layer 1
  k_gemm<true ><<<dim3(2, 256), 256, 0, stream>>>(x16, Wx0f, bx0f, xp1, 32768, 256, 256);
  k_ema<<<512, 128, 0, stream>>>(xp1, cb1);
  k_gemm<false><<<dim3(4, 256), 256, 0, stream>>>(cb1, Uc0f, nullptr, db1, 32768, 512, 256);
  k_scan<<<64, 128, 0, stream>>>(Vh0f, db1, hb1, fl1, hs1);
  // layer 2
  k_gemm<true ><<<dim3(2, 256), 256, 0, stream>>>(hs1, Wx1f, bx1f, xp2, 32768, 256, 512);
  k_ema<<<512, 128, 0, stream>>>(xp2, cb2);
  k_gemm<false><<<dim3(4, 256), 256, 0, stream>>>(cb2, Uc1f, nullptr, db2, 32768, 512, 256);
  k_scan<<<64, 128, 0, stream>>>(Vh1f, db2, hb2, fl2, nullptr);
  // head: h_511 (t=511 -> parity 1) is in the parity-1 half of hb2
  k_final<<<32, 64, 0, stream>>>(hb2 + 64 * 512, fcwf, fcbf, d_out, dmode);
}